// Round 7
// baseline (476.764 us; speedup 1.0000x reference)
//
#include <hip/hip_runtime.h>
#include <hip/hip_bf16.h>

// B=4, T=1024, E=512, H=8.
// cast5 -> Q,K proj + Vt (=Wv.x^T) via gemm_bt -> mask_cast (bf16)
//   -> fused_attn (flash, 32x32x16 MFMA, swapped-QK^T, 2qg x 4role waves)
//   -> out GEMM split-K=8 + reduce(+bias).
// Layouts: Q,K [b,t,h,e] ld 4096; Vt [h*e, b*t]; O [b,t,h*e]; M2 [b,q,k] bf16.

typedef short bf16x8 __attribute__((ext_vector_type(8)));
typedef float f32x4 __attribute__((ext_vector_type(4)));
typedef float f32x16 __attribute__((ext_vector_type(16)));

__device__ __forceinline__ unsigned short f2bf(float f) {
  unsigned int u = __float_as_uint(f);
  u += 0x7FFFu + ((u >> 16) & 1u);            // RNE, finite inputs
  return (unsigned short)(u >> 16);
}
__device__ __forceinline__ float bf2f(unsigned short s) {
  return __uint_as_float(((unsigned int)s) << 16);
}

typedef const __attribute__((address_space(1))) unsigned int* gas1_t;
typedef __attribute__((address_space(3))) unsigned int* las3_t;

__device__ __forceinline__ void gload16(const unsigned short* g, unsigned short* l) {
  __builtin_amdgcn_global_load_lds((gas1_t)g, (las3_t)l, 16, 0, 0);
}

__device__ __forceinline__ void store_val(unsigned short* p, float v) { *p = f2bf(v); }
__device__ __forceinline__ void store_val(float* p, float v) { *p = v; }

// ---------------- generic BT GEMM, 128x128 tile, BK=32, 4 waves ----------------
template<typename OutT, bool HAS_BIAS>
__global__ __launch_bounds__(256) void gemm_bt(
    const unsigned short* __restrict__ A, const unsigned short* __restrict__ B,
    OutT* __restrict__ C, const float* __restrict__ bias,
    int K, int lda, int ldb, int ldc, int zshift,
    long long sAb, long long sAh, long long sBb, long long sBh,
    long long sCb, long long sCh, float alpha)
{
  const int tid  = threadIdx.x;
  const int lane = tid & 63;
  const int wave = tid >> 6;
  const int wr = wave >> 1, wc = wave & 1;
  const int bb = blockIdx.z >> zshift, hh = blockIdx.z & ((1 << zshift) - 1);
  const long long m0 = (long long)blockIdx.y * 128;
  const long long n0 = (long long)blockIdx.x * 128;

  const unsigned short* Ab = A + bb * sAb + hh * sAh;
  const unsigned short* Bb = B + bb * sBb + hh * sBh;

  __shared__ __align__(16) unsigned short lds[8192];

  const int srow = wave * 16 + (tid & 15);
  const int skc  = ((tid >> 4) & 3) * 8;
  const unsigned short* gA = Ab + (size_t)(m0 + srow) * lda + skc;
  const unsigned short* gB = Bb + (size_t)(n0 + srow) * ldb + skc;
  const size_t aStep = (size_t)64 * lda;
  const size_t bStep = (size_t)64 * ldb;
  unsigned short* lA = lds + wave * 512;
  unsigned short* lB = lds + 4096 + wave * 512;

  f32x4 acc[4][4];
#pragma unroll
  for (int m = 0; m < 4; ++m)
#pragma unroll
    for (int n = 0; n < 4; ++n) acc[m][n] = (f32x4){0.f, 0.f, 0.f, 0.f};

  for (int k0 = 0; k0 < K; k0 += 32) {
    gload16(gA + k0,         lA);
    gload16(gA + aStep + k0, lA + 2048);
    gload16(gB + k0,         lB);
    gload16(gB + bStep + k0, lB + 2048);
    __syncthreads();

    bf16x8 af[4], bf[4];
    const bf16x8* sA = (const bf16x8*)lds;
    const bf16x8* sB = (const bf16x8*)(lds + 4096);
#pragma unroll
    for (int m = 0; m < 4; ++m) af[m] = sA[(wr * 4 + m) * 64 + lane];
#pragma unroll
    for (int n = 0; n < 4; ++n) bf[n] = sB[(wc * 4 + n) * 64 + lane];
#pragma unroll
    for (int m = 0; m < 4; ++m)
#pragma unroll
      for (int n = 0; n < 4; ++n)
        acc[m][n] = __builtin_amdgcn_mfma_f32_16x16x32_bf16(af[m], bf[n], acc[m][n], 0, 0, 0);
    __syncthreads();
  }

  OutT* Cb = C + bb * sCb + hh * sCh;
  const int r0 = (lane >> 4) * 4;
  const int cc = lane & 15;
#pragma unroll
  for (int m = 0; m < 4; ++m) {
#pragma unroll
    for (int n = 0; n < 4; ++n) {
      const long long col = n0 + wc * 64 + n * 16 + cc;
      const float bv = HAS_BIAS ? bias[col] : 0.0f;
#pragma unroll
      for (int r = 0; r < 4; ++r) {
        const long long row = m0 + wr * 64 + m * 16 + r0 + r;
        store_val(Cb + (size_t)row * ldc + col, acc[m][n][r] * alpha + bv);
      }
    }
  }
}

// ---------------- fused flash attention, 32x32x16 MFMA ----------------
// Block = (b,h) x 64 q-rows; 8 waves = 2 q-groups(32q, qg=wave&1) x 4 roles(wave>>1).
// QK^T: wave(qg,kq=role): S^T[32q x 32keys] via mfma(K-frag, Q-frag), acc=16 regs.
//   C/D (m74/m101): col=lane&31 (q), row=(reg&3)+8*(reg>>2)+4*(lane>>5) (key).
// Stats: 4-way kq combine via LDS. P[qg][32q][128k] pad-140 in LDS.
// PV: wave(qg,eq=role): o = 32q x 128e quarter = o[4] f32x16 (64 regs).
// LDS elems: K 2x16384 [0,32768) | V 2x16384 [32768,65536) | P 2x4480 [65536,74496)
//            sc 256 f32 [74496,75008). Total 150016 B -> 1 block/CU.
__global__ __launch_bounds__(512, 2) void fused_attn(
    const unsigned short* __restrict__ Q, const unsigned short* __restrict__ K,
    const unsigned short* __restrict__ Vt, const unsigned short* __restrict__ M2,
    unsigned short* __restrict__ O)
{
  const int tid  = threadIdx.x;
  const int lane = tid & 63, wave = tid >> 6;
  const int l31 = lane & 31, lhi2 = lane >> 5;
  const int qg = wave & 1, role = wave >> 1;
  const int n = blockIdx.x;
  const int x = n & 7, i = n >> 3;                 // XCD x gets bh in [4x,4x+4)
  const int bh = x * 4 + (i >> 4), qblk = i & 15;
  const int b = bh >> 3, h = bh & 7;
  const int q0 = qblk * 64;

  __shared__ __align__(16) unsigned short lds[75008];
  float* sc = (float*)(lds + 74496);               // 256 f32 stats

  const int q = q0 + qg * 32 + l31;                // this lane's q row
  const int qrow = b * 1024 + q;
  const unsigned short* Qp = Q + (size_t)qrow * 4096 + h * 512 + lhi2 * 8;
  const unsigned short* Kp = K + ((size_t)(b * 1024)) * 4096 + h * 512;
  const unsigned short* Vp = Vt + ((size_t)(h * 512)) * 4096 + b * 1024;
  const unsigned short* Mp = M2 + (size_t)qrow * 1024;
  unsigned short* Pg = lds + 65536 + qg * 4480 + l31 * 140;   // P row base

  // stage K slice s of tile t: 32 frags f=estep*4+kq, frag=[32keys x 16e]
  auto stageK = [&](int par, int t, int s) {
#pragma unroll
    for (int c = 0; c < 4; ++c) {
      const int f = wave * 4 + c;
      const int kq = f & 3, estep = f >> 2;
      const unsigned short* src = Kp + (size_t)(t * 128 + kq * 32 + l31) * 4096
                                     + s * 128 + estep * 16 + lhi2 * 8;
      gload16(src, lds + par * 16384 + f * 512);
    }
  };
  // stage V slice ks2 of tile t: 32 frags f=etile*2+kstep, frag=[32e x 16k]
  auto stageV = [&](int par, int t, int ks2) {
#pragma unroll
    for (int c = 0; c < 4; ++c) {
      const int f = wave * 4 + c;
      const int kstep = f & 1, etile = f >> 1;
      const unsigned short* src = Vp + (size_t)(etile * 32 + l31) * 4096
                                     + t * 128 + ks2 * 32 + kstep * 16 + lhi2 * 8;
      gload16(src, lds + 32768 + par * 16384 + f * 512);
    }
  };

  f32x16 o[4];
#pragma unroll
  for (int e = 0; e < 4; ++e)
#pragma unroll
    for (int j = 0; j < 16; ++j) o[e][j] = 0.f;
  float Mo = -3.0e38f, runS = 0.f;

  const float A2  = 0.044194173824159216f * 1.4426950408889634f;  // a*log2(e)
  const float L2E = 1.4426950408889634f;

  stageK(0, 0, 0);
  __syncthreads();

  for (int t = 0; t < 8; ++t) {
    // mask for this wave's key-quarter: 4 x 8B (4 bf16 = regs r03 0..3 of group j)
    uint2 mk[4];
#pragma unroll
    for (int j = 0; j < 4; ++j)
      mk[j] = *(const uint2*)(Mp + t * 128 + role * 32 + j * 8 + lhi2 * 4);

    // ---- QK^T: acc[r] = S[key = role*32 + (r&3)+8*(r>>2)+4*lhi2][q = l31] ----
    f32x16 acc;
#pragma unroll
    for (int j = 0; j < 16; ++j) acc[j] = 0.f;
#pragma unroll
    for (int s = 0; s < 4; ++s) {
      if (s < 3) stageK((s + 1) & 1, t, s + 1);
      else       stageV(0, t, 0);
      const unsigned short* kb = lds + (s & 1) * 16384;
#pragma unroll
      for (int estep = 0; estep < 8; ++estep) {
        const bf16x8 qf = *(const bf16x8*)(Qp + s * 128 + estep * 16);
        const bf16x8 af = *(const bf16x8*)(kb + (estep * 4 + role) * 512 + lane * 8);
        acc = __builtin_amdgcn_mfma_f32_32x32x16_bf16(af, qf, acc, 0, 0, 0);
      }
      __syncthreads();
    }

    // ---- logits (exp2 space) ----
#pragma unroll
    for (int j = 0; j < 4; ++j) {
      acc[j*4+0] = acc[j*4+0] * A2 - bf2f((unsigned short)(mk[j].x & 0xffffu)) * L2E;
      acc[j*4+1] = acc[j*4+1] * A2 - bf2f((unsigned short)(mk[j].x >> 16)) * L2E;
      acc[j*4+2] = acc[j*4+2] * A2 - bf2f((unsigned short)(mk[j].y & 0xffffu)) * L2E;
      acc[j*4+3] = acc[j*4+3] * A2 - bf2f((unsigned short)(mk[j].y >> 16)) * L2E;
    }

    // ---- per-q tile max: in-lane 16, xor32, then 4-way kq combine via LDS ----
    float pm = acc[0];
#pragma unroll
    for (int j = 1; j < 16; ++j) pm = fmaxf(pm, acc[j]);
    pm = fmaxf(pm, __shfl_xor(pm, 32));
    if (lane < 32) sc[(qg * 4 + role) * 32 + l31] = pm;
    __syncthreads();                               // B-stats
    const float Mt = fmaxf(fmaxf(sc[qg*128 + l31],      sc[qg*128 + 32 + l31]),
                           fmaxf(sc[qg*128 + 64 + l31], sc[qg*128 + 96 + l31]));
    const float Mn = fmaxf(Mo, Mt);
    const float fsc = exp2f(Mo - Mn);
    Mo = Mn;
    runS *= fsc;
#pragma unroll
    for (int e = 0; e < 4; ++e)
#pragma unroll
      for (int j = 0; j < 16; ++j) o[e][j] *= fsc;

    // ---- P = exp2(lg - Mn), write to LDS; partial row-sum ----
    float ps = 0.f;
#pragma unroll
    for (int j = 0; j < 4; ++j) {
      const float p0 = exp2f(acc[j*4+0] - Mn);
      const float p1 = exp2f(acc[j*4+1] - Mn);
      const float p2 = exp2f(acc[j*4+2] - Mn);
      const float p3 = exp2f(acc[j*4+3] - Mn);
      ps += (p0 + p1) + (p2 + p3);
      uint2 w;
      w.x = (unsigned int)f2bf(p0) | ((unsigned int)f2bf(p1) << 16);
      w.y = (unsigned int)f2bf(p2) | ((unsigned int)f2bf(p3) << 16);
      *(uint2*)(Pg + role * 32 + j * 8 + lhi2 * 4) = w;
    }
    ps += __shfl_xor(ps, 32);
    runS += ps;
    __syncthreads();                               // B-P: P complete, V0 staged

    // ---- PV: o[et] over e = role*128 + et*32, k-chunks ks2 of 32 ----
#pragma unroll
    for (int ks2 = 0; ks2 < 4; ++ks2) {
      if (ks2 < 3) stageV((ks2 + 1) & 1, t, ks2 + 1);
      else if (t < 7) stageK(0, t + 1, 0);
      const unsigned short* vb = lds + 32768 + (ks2 & 1) * 16384;
      bf16x8 pb[2];
#pragma unroll
      for (int kstep = 0; kstep < 2; ++kstep)
        pb[kstep] = *(const bf16x8*)(Pg + ks2 * 32 + kstep * 16 + lhi2 * 8);
#pragma unroll
      for (int et = 0; et < 4; ++et) {
        const int f = (role * 4 + et) * 2;
#pragma unroll
        for (int kstep = 0; kstep < 2; ++kstep) {
          const bf16x8 af = *(const bf16x8*)(vb + (f + kstep) * 512 + lane * 8);
          o[et] = __builtin_amdgcn_mfma_f32_32x32x16_bf16(af, pb[kstep], o[et], 0, 0, 0);
        }
      }
      __syncthreads();
    }
  }

  // ---- epilogue: 4-way kq sum combine, normalize, store O[q][e] ----
  if (lane < 32) sc[(qg * 4 + role) * 32 + l31] = runS;
  __syncthreads();
  const float tot = sc[qg*128 + l31] + sc[qg*128 + 32 + l31]
                  + sc[qg*128 + 64 + l31] + sc[qg*128 + 96 + l31];
  const float rinv = 1.0f / tot;
  unsigned short* Op = O + (size_t)qrow * 4096 + h * 512 + role * 128;
#pragma unroll
  for (int et = 0; et < 4; ++et) {
#pragma unroll
    for (int j = 0; j < 4; ++j) {
      uint2 w;
      w.x = (unsigned int)f2bf(o[et][j*4+0] * rinv) | ((unsigned int)f2bf(o[et][j*4+1] * rinv) << 16);
      w.y = (unsigned int)f2bf(o[et][j*4+2] * rinv) | ((unsigned int)f2bf(o[et][j*4+3] * rinv) << 16);
      *(uint2*)(Op + et * 32 + j * 8 + lhi2 * 4) = w;
    }
  }
}

// ---------------- split-K reduce: out = sum(partials) + bias ----------------
__global__ __launch_bounds__(256) void reduce_kernel(
    const float* __restrict__ P, const float* __restrict__ bias,
    float* __restrict__ out)
{
  const int i = blockIdx.x * 256 + threadIdx.x;
  const int col4 = i & 127;
  const float4* p4 = (const float4*)P + i;
  float4 s = p4[0];
#pragma unroll
  for (int z = 1; z < 8; ++z) {
    float4 v = p4[(size_t)z * 524288];
    s.x += v.x; s.y += v.y; s.z += v.z; s.w += v.w;
  }
  float4 b = ((const float4*)bias)[col4];
  s.x += b.x; s.y += b.y; s.z += b.z; s.w += b.w;
  ((float4*)out)[i] = s;
}

// ---------------- fused fp32 -> bf16 cast of all 5 tensors ----------------
__global__ __launch_bounds__(256) void cast5_kernel(
    const float* __restrict__ s0, const float* __restrict__ s1,
    const float* __restrict__ s2, const float* __restrict__ s3,
    const float* __restrict__ s4, unsigned short* __restrict__ dst)
{
  const int seg = blockIdx.x >> 11;
  const int off = (blockIdx.x & 2047) * 256 + threadIdx.x;
  const float* s = s0;
  if (seg == 1) s = s1; else if (seg == 2) s = s2;
  else if (seg == 3) s = s3; else if (seg == 4) s = s4;
  float4 v = ((const float4*)s)[off];
  ushort4 o;
  o.x = f2bf(v.x); o.y = f2bf(v.y); o.z = f2bf(v.z); o.w = f2bf(v.w);
  ((ushort4*)dst)[(size_t)seg * 524288 + off] = o;
}

// ---------------- mask fp32 -> bf16 cast ----------------
__global__ __launch_bounds__(256) void mask_cast(
    const float* __restrict__ mask, unsigned short* __restrict__ M2)
{
  const int i = blockIdx.x * 256 + threadIdx.x;   // 1M float4
  float4 v = ((const float4*)mask)[i];
  ushort4 o;
  o.x = f2bf(v.x); o.y = f2bf(v.y); o.z = f2bf(v.z); o.w = f2bf(v.w);
  ((ushort4*)M2)[i] = o;
}

extern "C" void kernel_launch(void* const* d_in, const int* in_sizes, int n_in,
                              void* d_out, int out_size, void* d_ws, size_t ws_size,
                              hipStream_t stream) {
  const float* x    = (const float*)d_in[0];
  const float* mask = (const float*)d_in[1];
  const float* Wk   = (const float*)d_in[2];
  const float* Wq   = (const float*)d_in[3];
  const float* Wv   = (const float*)d_in[4];
  const float* Wu   = (const float*)d_in[5];
  const float* bu   = (const float*)d_in[6];

  const size_t MB = 1024 * 1024;
  if (ws_size < 212 * MB) return;
  char* ws = (char*)d_ws;
  unsigned short* xb  = (unsigned short*)(ws + 0 * MB);    // 4MB  [4096,512]
  unsigned short* Wqb = (unsigned short*)(ws + 4 * MB);
  unsigned short* Wkb = (unsigned short*)(ws + 8 * MB);
  unsigned short* Wvb = (unsigned short*)(ws + 12 * MB);
  unsigned short* Wub = (unsigned short*)(ws + 16 * MB);
  unsigned short* Qb  = (unsigned short*)(ws + 20 * MB);   // 32MB [b,t,h,e]
  unsigned short* Kb  = (unsigned short*)(ws + 52 * MB);   // 32MB
  unsigned short* Vt  = (unsigned short*)(ws + 84 * MB);   // 32MB [h*e, b*t]
  unsigned short* Ob  = (unsigned short*)(ws + 180 * MB);  // 32MB [b,t,h*e]
  unsigned short* M2  = (unsigned short*)(ws + 4 * MB);    // 8MB, overlays Wqb/Wkb (dead post-proj)
  float* Pk = (float*)(ws + 20 * MB);  // split-K partials overlay Qb/Kb (dead post-attn)

  cast5_kernel<<<5 * 2048, 256, 0, stream>>>(x, Wq, Wk, Wv, Wu, xb);

  // Q = x.Wq^T, K = x.Wk^T   (M=N=4096, K=512)
  gemm_bt<unsigned short, false><<<dim3(32, 32, 1), 256, 0, stream>>>(
      xb, Wqb, Qb, nullptr, 512, 512, 512, 4096, 3, 0, 0, 0, 0, 0, 0, 1.0f);
  gemm_bt<unsigned short, false><<<dim3(32, 32, 1), 256, 0, stream>>>(
      xb, Wkb, Kb, nullptr, 512, 512, 512, 4096, 3, 0, 0, 0, 0, 0, 0, 1.0f);
  // Vt = Wv.x^T
  gemm_bt<unsigned short, false><<<dim3(32, 32, 1), 256, 0, stream>>>(
      Wvb, xb, Vt, nullptr, 512, 512, 512, 4096, 3, 0, 0, 0, 0, 0, 0, 1.0f);

  // bf16 mask (after projections; overlays dead Wqb/Wkb)
  mask_cast<<<4096, 256, 0, stream>>>(mask, M2);

  // fused flash attention: 512 blocks = 32 bh x 16 qblk (XCD-pinned), 512 thr
  fused_attn<<<512, 512, 0, stream>>>(Qb, Kb, Vt, M2, Ob);

  // out partials: split-K=8 over K=4096
  gemm_bt<float, false><<<dim3(4, 32, 8), 256, 0, stream>>>(
      Ob, Wub, Pk, nullptr, 512, 4096, 4096, 512, 0,
      512LL, 0, 512LL, 0, 2097152LL, 0, 1.0f);
  reduce_kernel<<<2048, 256, 0, stream>>>(Pk, bu, (float*)d_out);
}

// Round 8
// 314.620 us; speedup vs baseline: 1.5154x; 1.5154x over previous
//
#include <hip/hip_runtime.h>
#include <hip/hip_bf16.h>

// B=4, T=1024, E=512, H=8. Two-pass attention, all matmuls on one GEMM:
//   cast5 -> Q,K proj + Vt (=Wv.x^T) -> S=QK^T*a -> softmax(S-mask) in place
//   -> O=P.V -> out GEMM split-K=8 + reduce(+bias).
// gemm_bt2: C = alpha*A.B^T, 256x256 tile, BK=64, 512 thr / 8 waves (2M x 4N),
// per-wave 128x64 out (acc 128 regs -> AGPR). 2-barrier K-loop (proven safe).
// Layouts: Q,K [b,t,h,e] ld 4096; Vt [h*e, b*t]; S/P [b,h,q,k]; O [b,t,h*e].

typedef short bf16x8 __attribute__((ext_vector_type(8)));
typedef float f32x4 __attribute__((ext_vector_type(4)));
typedef unsigned short u16x8 __attribute__((ext_vector_type(8)));

__device__ __forceinline__ unsigned short f2bf(float f) {
  unsigned int u = __float_as_uint(f);
  u += 0x7FFFu + ((u >> 16) & 1u);            // RNE, finite inputs
  return (unsigned short)(u >> 16);
}
__device__ __forceinline__ float bf2f(unsigned short s) {
  return __uint_as_float(((unsigned int)s) << 16);
}

typedef const __attribute__((address_space(1))) unsigned int* gas1_t;
typedef __attribute__((address_space(3))) unsigned int* las3_t;

__device__ __forceinline__ void gload16(const unsigned short* g, unsigned short* l) {
  __builtin_amdgcn_global_load_lds((gas1_t)g, (las3_t)l, 16, 0, 0);
}

__device__ __forceinline__ void store_val(unsigned short* p, float v) { *p = f2bf(v); }
__device__ __forceinline__ void store_val(float* p, float v) { *p = v; }

// ---------------- 256x256-tile BT GEMM, BK=64, 8 waves ----------------
// LDS fragment-major: frag f = m*2+ks (A) holds rows m*16+l15, k-chunk
// ks*32+lhi*8 at slot lane -> staging is 16 rows x 64 contiguous bytes per
// wave-call (full cache lines), ds_read_b128 of a frag = 64 consecutive 16B
// slots (conflict-free). blockIdx.z: bb=z>>zshift, hh=z&((1<<zshift)-1).
template<typename OutT>
__global__ __launch_bounds__(512, 1) void gemm_bt2(
    const unsigned short* __restrict__ A, const unsigned short* __restrict__ B,
    OutT* __restrict__ C,
    int K, int lda, int ldb, int ldc, int zshift,
    long long sAb, long long sAh, long long sBb, long long sBh,
    long long sCb, long long sCh, float alpha)
{
  const int tid  = threadIdx.x;
  const int lane = tid & 63;
  const int wave = tid >> 6;
  const int l15 = lane & 15, lhi = lane >> 4;
  const int wm = wave >> 2, wn = wave & 3;           // 2M x 4N wave grid
  const int bb = blockIdx.z >> zshift, hh = blockIdx.z & ((1 << zshift) - 1);
  const long long m0 = (long long)blockIdx.y * 256;
  const long long n0 = (long long)blockIdx.x * 256;

  const unsigned short* Ab = A + bb * sAb + hh * sAh;
  const unsigned short* Bb = B + bb * sBb + hh * sBh;

  __shared__ __align__(16) unsigned short lds[65536];  // A [0,32768) B [32768,)

  f32x4 acc[8][4];
#pragma unroll
  for (int m = 0; m < 8; ++m)
#pragma unroll
    for (int n = 0; n < 4; ++n) acc[m][n] = (f32x4){0.f, 0.f, 0.f, 0.f};

  for (int k0 = 0; k0 < K; k0 += 64) {
    // stage A and B tiles: 4 frags each per wave
#pragma unroll
    for (int c = 0; c < 4; ++c) {
      const int f = c * 8 + wave;
      const int m = f >> 1, ks = f & 1;
      const unsigned short* gA = Ab + (size_t)(m0 + m * 16 + l15) * lda
                                    + k0 + ks * 32 + lhi * 8;
      gload16(gA, lds + f * 512);
    }
#pragma unroll
    for (int c = 0; c < 4; ++c) {
      const int f = c * 8 + wave;
      const int m = f >> 1, ks = f & 1;
      const unsigned short* gB = Bb + (size_t)(n0 + m * 16 + l15) * ldb
                                    + k0 + ks * 32 + lhi * 8;
      gload16(gB, lds + 32768 + f * 512);
    }
    __syncthreads();                                  // drains vmcnt(0)

#pragma unroll
    for (int ks = 0; ks < 2; ++ks) {
      bf16x8 af[8], bf[4];
#pragma unroll
      for (int mf = 0; mf < 8; ++mf)
        af[mf] = *(const bf16x8*)(lds + ((wm * 8 + mf) * 2 + ks) * 512 + lane * 8);
#pragma unroll
      for (int nf = 0; nf < 4; ++nf)
        bf[nf] = *(const bf16x8*)(lds + 32768 + ((wn * 4 + nf) * 2 + ks) * 512 + lane * 8);
#pragma unroll
      for (int mf = 0; mf < 8; ++mf)
#pragma unroll
        for (int nf = 0; nf < 4; ++nf)
          acc[mf][nf] = __builtin_amdgcn_mfma_f32_16x16x32_bf16(af[mf], bf[nf], acc[mf][nf], 0, 0, 0);
    }
    __syncthreads();
  }

  // C/D layout (m89/m91): col = lane&15, row = (lane>>4)*4 + reg
  OutT* Cb = C + bb * sCb + hh * sCh;
#pragma unroll
  for (int mf = 0; mf < 8; ++mf) {
#pragma unroll
    for (int nf = 0; nf < 4; ++nf) {
      const long long col = n0 + wn * 64 + nf * 16 + l15;
#pragma unroll
      for (int r = 0; r < 4; ++r) {
        const long long row = m0 + wm * 128 + mf * 16 + lhi * 4 + r;
        store_val(Cb + (size_t)row * ldc + col, acc[mf][nf][r] * alpha);
      }
    }
  }
}

// ---------------- split-K reduce: out = sum(partials) + bias ----------------
__global__ __launch_bounds__(256) void reduce_kernel(
    const float* __restrict__ P, const float* __restrict__ bias,
    float* __restrict__ out)
{
  const int i = blockIdx.x * 256 + threadIdx.x;      // 0..524287 float4s
  const int col4 = i & 127;
  const float4* p4 = (const float4*)P + i;
  float4 s = p4[0];
#pragma unroll
  for (int z = 1; z < 8; ++z) {
    float4 v = p4[(size_t)z * 524288];
    s.x += v.x; s.y += v.y; s.z += v.z; s.w += v.w;
  }
  float4 b = ((const float4*)bias)[col4];
  s.x += b.x; s.y += b.y; s.z += b.z; s.w += b.w;
  ((float4*)out)[i] = s;
}

// ---------------- fused fp32 -> bf16 cast of all 5 tensors ----------------
__global__ __launch_bounds__(256) void cast5_kernel(
    const float* __restrict__ s0, const float* __restrict__ s1,
    const float* __restrict__ s2, const float* __restrict__ s3,
    const float* __restrict__ s4, unsigned short* __restrict__ dst)
{
  const int seg = blockIdx.x >> 11;
  const int off = (blockIdx.x & 2047) * 256 + threadIdx.x;
  const float* s = s0;
  if (seg == 1) s = s1; else if (seg == 2) s = s2;
  else if (seg == 3) s = s3; else if (seg == 4) s = s4;
  float4 v = ((const float4*)s)[off];
  ushort4 o;
  o.x = f2bf(v.x); o.y = f2bf(v.y); o.z = f2bf(v.z); o.w = f2bf(v.w);
  ((ushort4*)dst)[(size_t)seg * 524288 + off] = o;
}

// ---------------- in-place row softmax over S (bf16), logit = S - mask ----------------
// one wave per 1024-wide row; 4 rows per block. S layout [b,h,q,k]; mask [b,q,k].
__global__ __launch_bounds__(256) void softmax_kernel(
    unsigned short* __restrict__ S, const float* __restrict__ mask)
{
  const int wave = threadIdx.x >> 6;
  const int lane = threadIdx.x & 63;
  const long long row = (long long)blockIdx.x * 4 + wave;   // 0..32767
  const int q = (int)(row & 1023);
  const int b = (int)(row >> 13);
  unsigned short* Srow = S + row * 1024;
  const float* mrow = mask + ((size_t)b * 1024 + q) * 1024;

  u16x8 sv0 = ((const u16x8*)Srow)[lane * 2];
  u16x8 sv1 = ((const u16x8*)Srow)[lane * 2 + 1];
  float mk[16];
  const float4* m4 = (const float4*)mrow + lane * 4;
#pragma unroll
  for (int t = 0; t < 4; ++t) {
    float4 v = m4[t];
    mk[t * 4 + 0] = v.x; mk[t * 4 + 1] = v.y; mk[t * 4 + 2] = v.z; mk[t * 4 + 3] = v.w;
  }

  float lg[16];
#pragma unroll
  for (int j = 0; j < 8; ++j) lg[j] = bf2f(sv0[j]) - mk[j];
#pragma unroll
  for (int j = 0; j < 8; ++j) lg[8 + j] = bf2f(sv1[j]) - mk[8 + j];

  float mx = lg[0];
#pragma unroll
  for (int j = 1; j < 16; ++j) mx = fmaxf(mx, lg[j]);
#pragma unroll
  for (int off = 32; off > 0; off >>= 1) mx = fmaxf(mx, __shfl_xor(mx, off));

  float ex[16], sm = 0.f;
#pragma unroll
  for (int j = 0; j < 16; ++j) { ex[j] = __expf(lg[j] - mx); sm += ex[j]; }
#pragma unroll
  for (int off = 32; off > 0; off >>= 1) sm += __shfl_xor(sm, off);
  const float rinv = 1.0f / sm;

  u16x8 o0, o1;
#pragma unroll
  for (int j = 0; j < 8; ++j) o0[j] = f2bf(ex[j] * rinv);
#pragma unroll
  for (int j = 0; j < 8; ++j) o1[j] = f2bf(ex[8 + j] * rinv);
  ((u16x8*)Srow)[lane * 2] = o0;
  ((u16x8*)Srow)[lane * 2 + 1] = o1;
}

extern "C" void kernel_launch(void* const* d_in, const int* in_sizes, int n_in,
                              void* d_out, int out_size, void* d_ws, size_t ws_size,
                              hipStream_t stream) {
  const float* x    = (const float*)d_in[0];
  const float* mask = (const float*)d_in[1];
  const float* Wk   = (const float*)d_in[2];
  const float* Wq   = (const float*)d_in[3];
  const float* Wv   = (const float*)d_in[4];
  const float* Wu   = (const float*)d_in[5];
  const float* bu   = (const float*)d_in[6];

  const size_t MB = 1024 * 1024;
  if (ws_size < 212 * MB) return;
  char* ws = (char*)d_ws;
  unsigned short* xb  = (unsigned short*)(ws + 0 * MB);    // 4MB  [4096,512]
  unsigned short* Wqb = (unsigned short*)(ws + 4 * MB);
  unsigned short* Wkb = (unsigned short*)(ws + 8 * MB);
  unsigned short* Wvb = (unsigned short*)(ws + 12 * MB);
  unsigned short* Wub = (unsigned short*)(ws + 16 * MB);
  unsigned short* Qb  = (unsigned short*)(ws + 20 * MB);   // 32MB [b,t,h,e]
  unsigned short* Kb  = (unsigned short*)(ws + 52 * MB);   // 32MB
  unsigned short* Vt  = (unsigned short*)(ws + 84 * MB);   // 32MB [h*e, b*t]
  unsigned short* Sb  = (unsigned short*)(ws + 116 * MB);  // 64MB [b,h,q,k]
  unsigned short* Ob  = (unsigned short*)(ws + 180 * MB);  // 32MB [b,t,h*e]
  float* Pk = (float*)(ws + 20 * MB);  // split-K partials overlay Qb/Kb (dead post-attn)

  cast5_kernel<<<5 * 2048, 256, 0, stream>>>(x, Wq, Wk, Wv, Wu, xb);

  // Q = x.Wq^T, K = x.Wk^T   (M=N=4096, K=512), 256 blocks each
  gemm_bt2<unsigned short><<<dim3(16, 16, 1), 512, 0, stream>>>(
      xb, Wqb, Qb, 512, 512, 512, 4096, 0, 0, 0, 0, 0, 0, 0, 1.0f);
  gemm_bt2<unsigned short><<<dim3(16, 16, 1), 512, 0, stream>>>(
      xb, Wkb, Kb, 512, 512, 512, 4096, 0, 0, 0, 0, 0, 0, 0, 1.0f);
  // Vt = Wv.x^T
  gemm_bt2<unsigned short><<<dim3(16, 16, 1), 512, 0, stream>>>(
      Wvb, xb, Vt, 512, 512, 512, 4096, 0, 0, 0, 0, 0, 0, 0, 1.0f);

  // S = (1/sqrt(512)) * Q.K^T per (b,h)   (M=N=1024, K=512, 32 batches)
  gemm_bt2<unsigned short><<<dim3(4, 4, 32), 512, 0, stream>>>(
      Qb, Kb, Sb, 512, 4096, 4096, 1024, 3,
      4194304LL, 512LL, 4194304LL, 512LL, 8388608LL, 1048576LL,
      0.044194173824159216f);

  // P = softmax(S - mask) in place
  softmax_kernel<<<8192, 256, 0, stream>>>(Sb, mask);

  // O = P.V   (M=1024, N=512, K=1024, 32 batches)
  gemm_bt2<unsigned short><<<dim3(2, 4, 32), 512, 0, stream>>>(
      Sb, Vt, Ob, 1024, 1024, 4096, 4096, 3,
      8388608LL, 1048576LL, 1024LL, 2097152LL, 4194304LL, 512LL, 1.0f);

  // out partials: split-K=8 over K=4096 (M=4096, N=512, slice=512)
  gemm_bt2<float><<<dim3(2, 16, 8), 512, 0, stream>>>(
      Ob, Wub, Pk, 512, 4096, 4096, 512, 0,
      512LL, 0, 512LL, 0, 2097152LL, 0, 1.0f);

  // out = sum_z Pk[z] + bu
  reduce_kernel<<<2048, 256, 0, stream>>>(Pk, bu, (float*)d_out);
}